// Round 1
// baseline (232.297 us; speedup 1.0000x reference)
//
#include <hip/hip_runtime.h>

#define TT 16
#define CC 320
#define NHEADS 8
#define DH 64
#define INNER 512

typedef float f32x4 __attribute__((ext_vector_type(4)));
typedef short bf16x8 __attribute__((ext_vector_type(8)));
typedef unsigned short u16;

__device__ __forceinline__ float bf2f(u16 u){
    union { unsigned int i; float f; } v; v.i = ((unsigned int)u) << 16; return v.f;
}
__device__ __forceinline__ u16 f2bf(float f){
    union { float f; unsigned int i; } v; v.f = f;
    unsigned int x = v.i;
    return (u16)((x + 0x7fffu + ((x >> 16) & 1u)) >> 16);   // RNE
}

// ---------------- kernel 1: weights fp32 -> bf16 (no transpose needed) ----------------
__global__ __launch_bounds__(256) void k_w2bf(const float* __restrict__ wq, const float* __restrict__ wk,
                                              const float* __restrict__ wv, const float* __restrict__ wo,
                                              u16* __restrict__ oq, u16* __restrict__ ok,
                                              u16* __restrict__ ov, u16* __restrict__ oo){
    const float* s; u16* d;
    switch (blockIdx.y){
        case 0: s = wq; d = oq; break;
        case 1: s = wk; d = ok; break;
        case 2: s = wv; d = ov; break;
        default: s = wo; d = oo; break;
    }
    int i = (blockIdx.x * 256 + threadIdx.x) * 4;  // 163840 elems per matrix, grid.x=160
    f32x4 v = *(const f32x4*)(s + i);
    d[i + 0] = f2bf(v[0]); d[i + 1] = f2bf(v[1]);
    d[i + 2] = f2bf(v[2]); d[i + 3] = f2bf(v[3]);
}

// ---------------- kernel 2: transpose + LayerNorm -> xn bf16 [s][t][c] ----------------
__global__ __launch_bounds__(256) void k_ln(const float* __restrict__ x, const float* __restrict__ lnw,
                                            const float* __restrict__ lnb, u16* __restrict__ xn){
    __shared__ float tile[CC][37];      // [c][w], stride 37 words -> bank spread
    __shared__ float psum[32][36];
    __shared__ float psq[32][36];
    __shared__ float meanb[32];
    __shared__ float rstdb[32];

    int wg = blockIdx.x;                 // (b,h,t)
    int t = wg & 15, h = (wg >> 4) & 31, b = wg >> 9;
    int tid = threadIdx.x;
    const size_t base = ((size_t)(b * CC) * TT + t) * 1024 + h * 32;  // +c*16384 + w

    // pass 1: load (coalesced float4 along w), stage in LDS, partial sums
    int w4 = (tid & 7) * 4, cg = tid >> 3;        // 8 w-quads x 32 c-groups
    f32x4 s4 = {0.f,0.f,0.f,0.f}, q4 = {0.f,0.f,0.f,0.f};
    for (int i = 0; i < 10; ++i){
        int c = cg * 10 + i;
        f32x4 v = *(const f32x4*)(x + base + (size_t)c * 16384 + w4);
        tile[c][w4 + 0] = v[0]; tile[c][w4 + 1] = v[1];
        tile[c][w4 + 2] = v[2]; tile[c][w4 + 3] = v[3];
        s4 += v; q4 += v * v;
    }
    psum[cg][w4 + 0] = s4[0]; psum[cg][w4 + 1] = s4[1]; psum[cg][w4 + 2] = s4[2]; psum[cg][w4 + 3] = s4[3];
    psq [cg][w4 + 0] = q4[0]; psq [cg][w4 + 1] = q4[1]; psq [cg][w4 + 2] = q4[2]; psq [cg][w4 + 3] = q4[3];
    __syncthreads();

    if (tid < 32){
        float s = 0.f, q = 0.f;
        for (int g = 0; g < 32; ++g){ s += psum[g][tid]; q += psq[g][tid]; }
        float mean = s * (1.f / CC);
        float var  = q * (1.f / CC) - mean * mean;
        meanb[tid] = mean;
        rstdb[tid] = rsqrtf(var + 1e-5f);
    }
    __syncthreads();

    // pass 2: normalize, write bf16 coalesced along c
    int cl = tid & 63, wq_ = tid >> 6;
    float lw[5], lb[5];
    #pragma unroll
    for (int ci = 0; ci < 5; ++ci){ lw[ci] = lnw[ci * 64 + cl]; lb[ci] = lnb[ci * 64 + cl]; }
    int s_base = (b * 32 + h) * 32;
    for (int wi = 0; wi < 8; ++wi){
        int w = wq_ * 8 + wi;
        float mean = meanb[w], rstd = rstdb[w];
        size_t rowoff = ((size_t)(s_base + w) * TT + t) * CC;
        #pragma unroll
        for (int ci = 0; ci < 5; ++ci){
            int c = ci * 64 + cl;
            float nv = (tile[c][w] - mean) * rstd * lw[ci] + lb[ci];
            xn[rowoff + c] = f2bf(nv);
        }
    }
}

// ---------------- kernel 3: fused QKV + attention + O-proj ----------------
// 4 samples per WG (M=64 rows), 4 waves (256 thr), mfma_f32_16x16x32_bf16
__global__ __launch_bounds__(256, 2) void k_attn(const u16* __restrict__ xng,
                                                 const u16* __restrict__ wq, const u16* __restrict__ wk,
                                                 const u16* __restrict__ wv, const u16* __restrict__ wo,
                                                 const float* __restrict__ bo, u16* __restrict__ proj){
    __shared__ u16 xn_s[64][328];   // [m][c] pad+8
    __shared__ u16 qh_s[64][72];    // [m][d]  (reused for attn output)
    __shared__ u16 kh_s[64][72];    // [m][d]
    __shared__ u16 vt_s[64][88];    // [d][m]  cols 64..79 zero (PV K=32 overrun)
    __shared__ u16 p_s[4][16][40];  // [wave][tq][tk] cols 16..31 zero

    int tid = threadIdx.x;
    int lane = tid & 63;
    int wid = tid >> 6;       // wave 0..3
    int l15 = lane & 15;
    int g4  = lane >> 4;      // 0..3
    int s0 = blockIdx.x * 4;

    // load xn tile (64 rows x 320 bf16, contiguous)
    {
        const u16* src = xng + (size_t)s0 * TT * CC;
        #pragma unroll
        for (int i = 0; i < 10; ++i){
            int ch = tid + 256 * i;              // 0..2559
            int r = ch / 40, cc8 = (ch % 40) * 8;
            *(bf16x8*)(&xn_s[r][cc8]) = *(const bf16x8*)(src + r * CC + cc8);
        }
        #pragma unroll
        for (int i = 0; i < 4; ++i){             // zero vt cols 64..79
            int idx = tid + 256 * i;             // 0..1023
            vt_s[idx >> 4][64 + (idx & 15)] = 0;
        }
        #pragma unroll
        for (int i = 0; i < 4; ++i){             // zero p cols 16..31
            int idx = tid + 256 * i;             // 0..1023
            int wgg = idx >> 8, rest = idx & 255;
            p_s[wgg][rest >> 4][16 + (rest & 15)] = 0;
        }
    }
    __syncthreads();

    f32x4 acco[5][4];
    #pragma unroll
    for (int j = 0; j < 5; ++j)
        #pragma unroll
        for (int mb = 0; mb < 4; ++mb) acco[j][mb] = (f32x4){0.f,0.f,0.f,0.f};

    const f32x4 zero4 = (f32x4){0.f,0.f,0.f,0.f};

    for (int hd = 0; hd < NHEADS; ++hd){
        // ---- merged Q,K,V^T GEMMs (K=320) ----
        f32x4 aq[4], ak[4], av[4];
        #pragma unroll
        for (int mb = 0; mb < 4; ++mb){ aq[mb] = zero4; ak[mb] = zero4; av[mb] = zero4; }
        const u16* wqrow = wq + ((size_t)(hd * DH + wid * 16 + l15)) * CC + g4 * 8;
        const u16* wkrow = wk + ((size_t)(hd * DH + wid * 16 + l15)) * CC + g4 * 8;
        const u16* wvrow = wv + ((size_t)(hd * DH + wid * 16 + l15)) * CC + g4 * 8;
        for (int k0 = 0; k0 < CC; k0 += 32){
            bf16x8 bq = *(const bf16x8*)(wqrow + k0);
            bf16x8 bk = *(const bf16x8*)(wkrow + k0);
            bf16x8 aw = *(const bf16x8*)(wvrow + k0);
            #pragma unroll
            for (int mb = 0; mb < 4; ++mb){
                bf16x8 xa = *(const bf16x8*)(&xn_s[mb * 16 + l15][k0 + g4 * 8]);
                aq[mb] = __builtin_amdgcn_mfma_f32_16x16x32_bf16(xa, bq, aq[mb], 0, 0, 0);
                ak[mb] = __builtin_amdgcn_mfma_f32_16x16x32_bf16(xa, bk, ak[mb], 0, 0, 0);
                av[mb] = __builtin_amdgcn_mfma_f32_16x16x32_bf16(aw, xa, av[mb], 0, 0, 0); // V^T = Wv_h * xn^T
            }
        }
        // write Q (pre-scaled), K, V^T tiles
        #pragma unroll
        for (int mb = 0; mb < 4; ++mb){
            #pragma unroll
            for (int r = 0; r < 4; ++r){
                int row = mb * 16 + g4 * 4 + r;
                qh_s[row][wid * 16 + l15] = f2bf(aq[mb][r] * 0.125f);
                kh_s[row][wid * 16 + l15] = f2bf(ak[mb][r]);
                vt_s[wid * 16 + g4 * 4 + r][mb * 16 + l15] = f2bf(av[mb][r]);
            }
        }
        __syncthreads();   // (1) tiles visible to all waves

        // ---- scores for sample g = wid (16x16, K=64) ----
        f32x4 sc = zero4;
        #pragma unroll
        for (int k0 = 0; k0 < DH; k0 += 32){
            bf16x8 qa = *(const bf16x8*)(&qh_s[wid * 16 + l15][k0 + g4 * 8]);
            bf16x8 kb = *(const bf16x8*)(&kh_s[wid * 16 + l15][k0 + g4 * 8]);
            sc = __builtin_amdgcn_mfma_f32_16x16x32_bf16(qa, kb, sc, 0, 0, 0);
        }
        // softmax over tk (= lanes within 16-group), rows in regs
        f32x4 pr;
        #pragma unroll
        for (int r = 0; r < 4; ++r){
            float m = sc[r];
            m = fmaxf(m, __shfl_xor(m, 1)); m = fmaxf(m, __shfl_xor(m, 2));
            m = fmaxf(m, __shfl_xor(m, 4)); m = fmaxf(m, __shfl_xor(m, 8));
            float e = __expf(sc[r] - m);
            float s = e;
            s += __shfl_xor(s, 1); s += __shfl_xor(s, 2);
            s += __shfl_xor(s, 4); s += __shfl_xor(s, 8);
            pr[r] = e / s;
        }
        #pragma unroll
        for (int r = 0; r < 4; ++r) p_s[wid][g4 * 4 + r][l15] = f2bf(pr[r]);

        // ---- PV (K=32, zero-padded) — per-wave private p_s + shared vt_s ----
        bf16x8 pa = *(const bf16x8*)(&p_s[wid][l15][g4 * 8]);
        f32x4 at[4];
        #pragma unroll
        for (int nb = 0; nb < 4; ++nb){
            bf16x8 vb = *(const bf16x8*)(&vt_s[nb * 16 + l15][wid * 16 + g4 * 8]);
            at[nb] = __builtin_amdgcn_mfma_f32_16x16x32_bf16(pa, vb, zero4, 0, 0, 0);
        }
        __syncthreads();   // (2) all waves done reading qh/kh before overwrite
        #pragma unroll
        for (int nb = 0; nb < 4; ++nb)
            #pragma unroll
            for (int r = 0; r < 4; ++r)
                qh_s[wid * 16 + g4 * 4 + r][nb * 16 + l15] = f2bf(at[nb][r]);
        __syncthreads();   // (3a) attn visible to all waves

        // ---- O-proj partial: acc += attn_h[64x64] @ Wo[:, hd*64:+64]^T ----
        #pragma unroll
        for (int k0 = 0; k0 < DH; k0 += 32){
            bf16x8 af[4];
            #pragma unroll
            for (int mb = 0; mb < 4; ++mb)
                af[mb] = *(const bf16x8*)(&qh_s[mb * 16 + l15][k0 + g4 * 8]);
            #pragma unroll
            for (int j = 0; j < 5; ++j){
                bf16x8 bw = *(const bf16x8*)(wo + ((size_t)((wid * 5 + j) * 16 + l15)) * INNER + hd * DH + k0 + g4 * 8);
                #pragma unroll
                for (int mb = 0; mb < 4; ++mb)
                    acco[j][mb] = __builtin_amdgcn_mfma_f32_16x16x32_bf16(af[mb], bw, acco[j][mb], 0, 0, 0);
            }
        }
        __syncthreads();   // (3b) O-proj reads done before next head's writes
    }

    // epilogue: proj[s][t][c] = acc + bo  (bf16)
    #pragma unroll
    for (int j = 0; j < 5; ++j){
        int c = (wid * 5 + j) * 16 + l15;
        float bias = bo[c];
        #pragma unroll
        for (int mb = 0; mb < 4; ++mb){
            size_t rowbase = ((size_t)(s0 + mb) * TT) * CC;
            #pragma unroll
            for (int r = 0; r < 4; ++r){
                int t = g4 * 4 + r;
                proj[rowbase + (size_t)t * CC + c] = f2bf(acco[j][mb][r] + bias);
            }
        }
    }
}

// ---------------- kernel 4: residual + transpose back to (b,c,t,h,w) ----------------
__global__ __launch_bounds__(256) void k_res(const u16* __restrict__ proj, const float* __restrict__ x,
                                             float* __restrict__ out){
    __shared__ u16 tile[32][328];   // [w][c]
    int wg = blockIdx.x;
    int t = wg & 15, h = (wg >> 4) & 31, b = wg >> 9;
    int tid = threadIdx.x;
    int s0 = (b * 32 + h) * 32;
    #pragma unroll
    for (int i = 0; i < 5; ++i){
        int ch = tid + 256 * i;                 // 0..1279
        int w = ch / 40, cc8 = (ch % 40) * 8;
        *(bf16x8*)(&tile[w][cc8]) = *(const bf16x8*)(proj + ((size_t)(s0 + w) * TT + t) * CC + cc8);
    }
    __syncthreads();
    int w = tid & 31, cq = tid >> 5;
    size_t base = ((size_t)(b * CC) * TT + t) * 1024 + h * 32 + w;
    for (int i = 0; i < 40; ++i){
        int c = cq * 40 + i;
        size_t idx = base + (size_t)c * 16384;
        out[idx] = x[idx] + bf2f(tile[w][c]);
    }
}

extern "C" void kernel_launch(void* const* d_in, const int* in_sizes, int n_in,
                              void* d_out, int out_size, void* d_ws, size_t ws_size,
                              hipStream_t stream){
    const float* hid = (const float*)d_in[0];
    const float* lnw = (const float*)d_in[1];
    const float* lnb = (const float*)d_in[2];
    const float* Wq  = (const float*)d_in[3];
    const float* Wk  = (const float*)d_in[4];
    const float* Wv  = (const float*)d_in[5];
    const float* Wo  = (const float*)d_in[6];
    const float* bo  = (const float*)d_in[7];

    char* ws = (char*)d_ws;
    const size_t WN = 163840;             // elements per weight matrix
    u16* wq_b = (u16*)ws;
    u16* wk_b = wq_b + WN;
    u16* wv_b = wk_b + WN;
    u16* wo_b = wv_b + WN;
    u16* xn   = wo_b + WN;                         // 4096*16*320 bf16
    u16* proj = xn + (size_t)4096 * TT * CC;       // 4096*16*320 bf16

    k_w2bf<<<dim3(160, 4), 256, 0, stream>>>(Wq, Wk, Wv, Wo, wq_b, wk_b, wv_b, wo_b);
    k_ln  <<<2048, 256, 0, stream>>>(hid, lnw, lnb, xn);
    k_attn<<<1024, 256, 0, stream>>>(xn, wq_b, wk_b, wv_b, wo_b, bo, proj);
    k_res <<<2048, 256, 0, stream>>>(proj, hid, (float*)d_out);
}